// Round 2
// baseline (439.985 us; speedup 1.0000x reference)
//
#include <hip/hip_runtime.h>
#include <math.h>

#define B_ 4096
#define T_ 64
#define DIN_ 300
#define H_ 3
#define NF4 75  // float4s per x row (300 floats = 1200 B)

// ws layout: [0,16KB) len32 | [64KB, 64KB+3MB) xb[T][B][3] f32
#define XB_OFF 65536

// ---------------------------------------------------------------------------
// Normalize lengths to int32, auto-detecting int32 vs int64 source layout.
// Valid lengths in [1,64]; int64 => every odd 32-bit word is 0 (L>=1 makes
// this unambiguous).
__global__ void prep_lengths_kernel(const int* __restrict__ lraw,
                                    int* __restrict__ len32, int B) {
  __shared__ int flag;
  if (threadIdx.x == 0) flag = 0;
  __syncthreads();
  int local = 0;
  int half = B >> 1;
  for (int i = threadIdx.x; i < half; i += blockDim.x)
    if (lraw[2 * i + 1] != 0) local = 1;
  if (local) atomicOr(&flag, 1);
  __syncthreads();
  int is32 = flag;
  for (int i = threadIdx.x; i < B; i += blockDim.x) {
    int v = is32 ? lraw[i] : lraw[2 * i];
    if (v < 1) v = 1;
    if (v > T_) v = T_;
    len32[i] = v;
  }
}

// ---------------------------------------------------------------------------
// Projection: xb[t][b][h] = x[b,t,:] . W_ih[h,:]   (bias folded into tail)
// One block (4 waves) per sample. Wave w covers rows [16w, 16w+16).
// Quad mapping: 4 lanes per row, lane sub-slot s takes float4 idx = 4k+s
// => only a 2-level shuffle reduce (vs 6-level for 64-lane reduce).
// Rows t >= L are skipped entirely (this is the HBM saving).
__global__ __launch_bounds__(256) void proj_kernel(
    const float* __restrict__ x,     // [B,T,DIN]
    const int* __restrict__ len,     // [B]
    const float* __restrict__ W_ih,  // [H,DIN]
    float* __restrict__ xb) {        // [T][B][H]
  const int b = blockIdx.x;
  const int tid = threadIdx.x;

  __shared__ float4 Wl[H_][76];  // 3.6 KB, broadcast-read (conflict-free)
  if (tid < H_ * NF4) {
    int h = tid / NF4;
    int i = tid - h * NF4;
    Wl[h][i] = reinterpret_cast<const float4*>(W_ih)[h * NF4 + i];
  }
  const int L = len[b];
  __syncthreads();

  const int wave = tid >> 6;
  const int lane = tid & 63;
  const int g = lane >> 2;  // row within this wave's 16-row chunk
  const int s = lane & 3;   // sub-slot within quad
  const int row = wave * 16 + g;
  if (wave * 16 >= L) return;  // wave-uniform early exit

  const bool rowok = (row < L);
  const float4* xr = reinterpret_cast<const float4*>(
      x + (size_t)b * (T_ * DIN_) + (size_t)row * DIN_);

  float a0 = 0.f, a1 = 0.f, a2 = 0.f;
#pragma unroll 4
  for (int k = 0; k < 19; ++k) {
    int idx = 4 * k + s;
    if (rowok && idx < NF4) {
      float4 v = xr[idx];
      float4 w0 = Wl[0][idx];
      float4 w1 = Wl[1][idx];
      float4 w2 = Wl[2][idx];
      a0 += v.x * w0.x + v.y * w0.y + v.z * w0.z + v.w * w0.w;
      a1 += v.x * w1.x + v.y * w1.y + v.z * w1.z + v.w * w1.w;
      a2 += v.x * w2.x + v.y * w2.y + v.z * w2.z + v.w * w2.w;
    }
  }
  // quad reduce (lanes s=0..3): xor-1 then xor-2 stay within the quad
  a0 += __shfl_xor(a0, 1);
  a1 += __shfl_xor(a1, 1);
  a2 += __shfl_xor(a2, 1);
  a0 += __shfl_xor(a0, 2);
  a1 += __shfl_xor(a1, 2);
  a2 += __shfl_xor(a2, 2);

  if (s == 0 && rowok) {
    float* o = xb + ((size_t)row * B_ + b) * H_;
    o[0] = a0;
    o[1] = a1;
    o[2] = a2;
  }
}

// ---------------------------------------------------------------------------
// tanh(x) = (e^{2x}-1)/(e^{2x}+1), ~30-cycle chain vs ~100+ for ocml tanhf.
// Clamp keeps exp in range; tanh(9) rounds to 1.0f anyway.
__device__ __forceinline__ float fast_tanh(float x) {
  float xc = fminf(fmaxf(x, -9.0f), 9.0f);
  float t = __expf(2.0f * xc);  // v_exp_f32
  return (t - 1.0f) * __builtin_amdgcn_rcpf(t + 1.0f);
}

// Recurrence: one THREAD per sample -> 4096-wide parallel, no serial tail
// blocking a whole block. xb[t][b][h] layout makes lane-consecutive reads
// contiguous (12 B/lane per step).
__global__ __launch_bounds__(256) void tail_kernel(
    const int* __restrict__ len, const float* __restrict__ xb,
    const float* __restrict__ W_hh, const float* __restrict__ b_ih,
    const float* __restrict__ b_hh, float* __restrict__ out) {
  const int b = blockIdx.x * blockDim.x + threadIdx.x;
  if (b >= B_) return;
  const float w00 = W_hh[0], w01 = W_hh[1], w02 = W_hh[2];
  const float w10 = W_hh[3], w11 = W_hh[4], w12 = W_hh[5];
  const float w20 = W_hh[6], w21 = W_hh[7], w22 = W_hh[8];
  const float c0 = b_ih[0] + b_hh[0];
  const float c1 = b_ih[1] + b_hh[1];
  const float c2 = b_ih[2] + b_hh[2];
  const int L = len[b];
  float h0 = 0.f, h1 = 0.f, h2 = 0.f;
  const float* p = xb + (size_t)b * H_;
  for (int t = 0; t < L; ++t) {
    const float* q = p + (size_t)t * (B_ * H_);
    float a0 = q[0] + c0 + w00 * h0 + w01 * h1 + w02 * h2;
    float a1 = q[1] + c1 + w10 * h0 + w11 * h1 + w12 * h2;
    float a2 = q[2] + c2 + w20 * h0 + w21 * h1 + w22 * h2;
    h0 = fast_tanh(a0);
    h1 = fast_tanh(a1);
    h2 = fast_tanh(a2);
  }
  out[b * 3 + 0] = h0;
  out[b * 3 + 1] = h1;
  out[b * 3 + 2] = h2;
}

// ---------------------------------------------------------------------------
extern "C" void kernel_launch(void* const* d_in, const int* in_sizes, int n_in,
                              void* d_out, int out_size, void* d_ws,
                              size_t ws_size, hipStream_t stream) {
  const float* x = (const float*)d_in[0];
  const int* lraw = (const int*)d_in[1];
  const float* W_ih = (const float*)d_in[2];
  const float* W_hh = (const float*)d_in[3];
  const float* b_ih = (const float*)d_in[4];
  const float* b_hh = (const float*)d_in[5];
  float* out = (float*)d_out;

  int* len32 = (int*)d_ws;
  float* xb = (float*)((char*)d_ws + XB_OFF);

  prep_lengths_kernel<<<1, 256, 0, stream>>>(lraw, len32, B_);
  proj_kernel<<<B_, 256, 0, stream>>>(x, len32, W_ih, xb);
  tail_kernel<<<(B_ + 255) / 256, 256, 0, stream>>>(len32, xb, W_hh, b_ih,
                                                    b_hh, out);
}

// Round 3
// 414.198 us; speedup vs baseline: 1.0623x; 1.0623x over previous
//
#include <hip/hip_runtime.h>
#include <math.h>

#define B_ 4096
#define T_ 64
#define DIN_ 300
#define H_ 3
#define NF4 75  // float4s per x row (300 floats = 1200 B)

// tanh(x) = (e^{2x}-1)/(e^{2x}+1); clamp keeps exp in range (tanh(9) == 1.0f
// in f32 anyway). ~30-cycle chain vs ~100+ for ocml tanhf.
__device__ __forceinline__ float fast_tanh(float x) {
  float xc = fminf(fmaxf(x, -9.0f), 9.0f);
  float t = __expf(2.0f * xc);  // v_exp_f32
  return (t - 1.0f) * __builtin_amdgcn_rcpf(t + 1.0f);
}

// One block per sample. Phase 1: 4 waves compute xb[t][h] = x[b,t,:].W_ih[h,:]
// for t < L into LDS (quad mapping: 4 lanes per row -> 2-level shuffle
// reduce). Rows t >= L are never fetched (the HBM saving; avg L = 32.5 of
// 64). Phase 2: thread 0 runs the 3-wide recurrence from LDS with a
// one-step software prefetch, other waves exit.
//
// Lengths dtype auto-detect folded in: lengths ∈ [1,64], so if the raw
// buffer is int32, word 1 = lengths[1] != 0; if int64, word 1 is the high
// half of lengths[0] == 0. Single broadcast read, in-bounds either way.
__global__ __launch_bounds__(256) void rnn_fused_kernel(
    const float* __restrict__ x,     // [B,T,DIN]
    const int* __restrict__ lraw,    // [B] int32 or int64 (auto-detected)
    const float* __restrict__ W_ih,  // [H,DIN]
    const float* __restrict__ W_hh,  // [H,H]
    const float* __restrict__ b_ih,  // [H]
    const float* __restrict__ b_hh,  // [H]
    float* __restrict__ out) {       // [B,H]
  const int b = blockIdx.x;
  const int tid = threadIdx.x;

  __shared__ float4 Wl[H_][76];   // W_ih staged, broadcast reads
  __shared__ float4 xb_s[T_];     // xb[t] = {p0,p1,p2,unused}

  if (tid < H_ * NF4) {
    int h = tid / NF4;
    int i = tid - h * NF4;
    Wl[h][i] = reinterpret_cast<const float4*>(W_ih)[h * NF4 + i];
  }

  const bool is32 = (lraw[1] != 0);
  int L = is32 ? lraw[b] : lraw[2 * b];
  if (L < 1) L = 1;
  if (L > T_) L = T_;
  __syncthreads();

  const int wave = tid >> 6;
  const int lane = tid & 63;
  const int g = lane >> 2;  // row within this wave's 16-row chunk
  const int s = lane & 3;   // sub-slot within quad
  const int row = wave * 16 + g;

  if (wave * 16 < L) {  // wave-uniform: skip whole wave past L
    const bool rowok = (row < L);
    const float4* xr = reinterpret_cast<const float4*>(
        x + (size_t)b * (T_ * DIN_) + (size_t)row * DIN_);

    float a0 = 0.f, a1 = 0.f, a2 = 0.f;
#pragma unroll 4
    for (int k = 0; k < 19; ++k) {
      int idx = 4 * k + s;
      if (rowok && idx < NF4) {  // idx<NF4 fails only at k=18,s=3
        float4 v = xr[idx];
        float4 w0 = Wl[0][idx];
        float4 w1 = Wl[1][idx];
        float4 w2 = Wl[2][idx];
        a0 += v.x * w0.x + v.y * w0.y + v.z * w0.z + v.w * w0.w;
        a1 += v.x * w1.x + v.y * w1.y + v.z * w1.z + v.w * w1.w;
        a2 += v.x * w2.x + v.y * w2.y + v.z * w2.z + v.w * w2.w;
      }
    }
    // quad reduce: xor-1, xor-2 stay within the 4-lane group
    a0 += __shfl_xor(a0, 1);
    a1 += __shfl_xor(a1, 1);
    a2 += __shfl_xor(a2, 1);
    a0 += __shfl_xor(a0, 2);
    a1 += __shfl_xor(a1, 2);
    a2 += __shfl_xor(a2, 2);
    if (s == 0 && rowok) xb_s[row] = make_float4(a0, a1, a2, 0.f);
  }
  __syncthreads();

  if (tid != 0) return;  // waves 1-3 + lanes free their slots

  const float w00 = W_hh[0], w01 = W_hh[1], w02 = W_hh[2];
  const float w10 = W_hh[3], w11 = W_hh[4], w12 = W_hh[5];
  const float w20 = W_hh[6], w21 = W_hh[7], w22 = W_hh[8];
  const float c0 = b_ih[0] + b_hh[0];
  const float c1 = b_ih[1] + b_hh[1];
  const float c2 = b_ih[2] + b_hh[2];
  float h0 = 0.f, h1 = 0.f, h2 = 0.f;
  float4 cur = xb_s[0];
  for (int t = 0; t < L; ++t) {
    float4 nxt = xb_s[(t + 1 < L) ? t + 1 : t];  // prefetch hides ds_read
    float a0 = cur.x + c0 + w00 * h0 + w01 * h1 + w02 * h2;
    float a1 = cur.y + c1 + w10 * h0 + w11 * h1 + w12 * h2;
    float a2 = cur.z + c2 + w20 * h0 + w21 * h1 + w22 * h2;
    h0 = fast_tanh(a0);
    h1 = fast_tanh(a1);
    h2 = fast_tanh(a2);
    cur = nxt;
  }
  out[b * 3 + 0] = h0;
  out[b * 3 + 1] = h1;
  out[b * 3 + 2] = h2;
}

extern "C" void kernel_launch(void* const* d_in, const int* in_sizes, int n_in,
                              void* d_out, int out_size, void* d_ws,
                              size_t ws_size, hipStream_t stream) {
  const float* x = (const float*)d_in[0];
  const int* lraw = (const int*)d_in[1];
  const float* W_ih = (const float*)d_in[2];
  const float* W_hh = (const float*)d_in[3];
  const float* b_ih = (const float*)d_in[4];
  const float* b_hh = (const float*)d_in[5];
  float* out = (float*)d_out;

  rnn_fused_kernel<<<B_, 256, 0, stream>>>(x, lraw, W_ih, W_hh, b_ih, b_hh,
                                           out);
}

// Round 4
// 400.411 us; speedup vs baseline: 1.0988x; 1.0344x over previous
//
#include <hip/hip_runtime.h>
#include <math.h>

#define B_ 4096
#define T_ 64
#define DIN_ 300
#define H_ 3
#define NF4 75  // float4s per x row (300 floats = 1200 B)

// tanh(x) = (e^{2x}-1)/(e^{2x}+1); clamp keeps exp in range (tanh(9) == 1.0f
// in f32 anyway). ~30-cycle chain vs ~100+ for ocml tanhf.
__device__ __forceinline__ float fast_tanh(float x) {
  float xc = fminf(fmaxf(x, -9.0f), 9.0f);
  float t = __expf(2.0f * xc);  // v_exp_f32
  return (t - 1.0f) * __builtin_amdgcn_rcpf(t + 1.0f);
}

// One block per sample.
// Phase 1: 16 lanes per row (slot s = lane&15 owns float4 idx 16k+s, k<5).
//   W_ih fragment is REGISTER-resident (15 float4 = 60 VGPR/lane, loaded
//   once from global, L1/L2-served) -> zero LDS reads in the stream loop,
//   which was the ~18 us second bottleneck in R3 (3x ds_read_b128 per
//   k-iter). Global x reads are 4 x 256 B contiguous segments per instr.
//   Rows t >= L are never fetched (avg L = 32.5 of 64 -> halves HBM).
// Phase 2: thread 0 runs the 3-wide recurrence from LDS with one-step
//   prefetch; other threads exit.
__global__ __launch_bounds__(256) void rnn_fused_kernel(
    const float* __restrict__ x,     // [B,T,DIN]
    const int* __restrict__ lraw,    // [B] int32 or int64 (auto-detected)
    const float* __restrict__ W_ih,  // [H,DIN]
    const float* __restrict__ W_hh,  // [H,H]
    const float* __restrict__ b_ih,  // [H]
    const float* __restrict__ b_hh,  // [H]
    float* __restrict__ out) {       // [B,H]
  const int b = blockIdx.x;
  const int tid = threadIdx.x;
  const int wave = tid >> 6;
  const int lane = tid & 63;
  const int grp = lane >> 4;  // which of 4 rows this wave handles per pass
  const int s = lane & 15;    // float4 sub-slot within the row

  __shared__ float4 xb_s[T_];  // xb[t] = {p0,p1,p2,unused}

  // Lengths dtype auto-detect: lengths ∈ [1,64]; int32 => word1 = len[1] != 0,
  // int64 => word1 = high half of len[0] == 0. In-bounds either way.
  const bool is32 = (lraw[1] != 0);
  int L = is32 ? lraw[b] : lraw[2 * b];
  if (L < 1) L = 1;
  if (L > T_) L = T_;

  // Per-lane register W fragment: w[h][k] = W_ih[h].float4[16k+s].
  // k<4 always valid (idx <= 63); k=4 valid iff 64+s < 75 (s < 11).
  const float4* W4 = reinterpret_cast<const float4*>(W_ih);
  float4 w[H_][5];
#pragma unroll
  for (int h = 0; h < H_; ++h) {
#pragma unroll
    for (int k = 0; k < 4; ++k) w[h][k] = W4[h * NF4 + 16 * k + s];
    w[h][4] = (s < 11) ? W4[h * NF4 + 64 + s]
                       : make_float4(0.f, 0.f, 0.f, 0.f);
  }

  const float* xbase = x + (size_t)b * (T_ * DIN_);
  // Wave w covers rows {base + grp : base = 4w, 4w+16, 4w+32, 4w+48} < L.
  for (int base = wave * 4; base < L; base += 16) {
    const int row = base + grp;
    const bool rowok = (row < L);
    const float4* xr =
        reinterpret_cast<const float4*>(xbase + (size_t)row * DIN_);
    float a0 = 0.f, a1 = 0.f, a2 = 0.f;
    if (rowok) {
      float4 v[5];
#pragma unroll
      for (int k = 0; k < 4; ++k) v[k] = xr[16 * k + s];
      v[4] = (s < 11) ? xr[64 + s] : make_float4(0.f, 0.f, 0.f, 0.f);
#pragma unroll
      for (int k = 0; k < 5; ++k) {
        a0 += v[k].x * w[0][k].x + v[k].y * w[0][k].y + v[k].z * w[0][k].z +
              v[k].w * w[0][k].w;
        a1 += v[k].x * w[1][k].x + v[k].y * w[1][k].y + v[k].z * w[1][k].z +
              v[k].w * w[1][k].w;
        a2 += v[k].x * w[2][k].x + v[k].y * w[2][k].y + v[k].z * w[2][k].z +
              v[k].w * w[2][k].w;
      }
    }
    // reduce across the 16 lanes of this row (xor 1,2,4,8 stay in-group)
#pragma unroll
    for (int off = 1; off <= 8; off <<= 1) {
      a0 += __shfl_xor(a0, off);
      a1 += __shfl_xor(a1, off);
      a2 += __shfl_xor(a2, off);
    }
    if (s == 0 && rowok) xb_s[row] = make_float4(a0, a1, a2, 0.f);
  }
  __syncthreads();

  if (tid != 0) return;

  const float w00 = W_hh[0], w01 = W_hh[1], w02 = W_hh[2];
  const float w10 = W_hh[3], w11 = W_hh[4], w12 = W_hh[5];
  const float w20 = W_hh[6], w21 = W_hh[7], w22 = W_hh[8];
  const float c0 = b_ih[0] + b_hh[0];
  const float c1 = b_ih[1] + b_hh[1];
  const float c2 = b_ih[2] + b_hh[2];
  float h0 = 0.f, h1 = 0.f, h2 = 0.f;
  float4 cur = xb_s[0];
  for (int t = 0; t < L; ++t) {
    float4 nxt = xb_s[(t + 1 < L) ? t + 1 : t];  // prefetch hides ds_read
    float a0 = cur.x + c0 + w00 * h0 + w01 * h1 + w02 * h2;
    float a1 = cur.y + c1 + w10 * h0 + w11 * h1 + w12 * h2;
    float a2 = cur.z + c2 + w20 * h0 + w21 * h1 + w22 * h2;
    h0 = fast_tanh(a0);
    h1 = fast_tanh(a1);
    h2 = fast_tanh(a2);
    cur = nxt;
  }
  out[b * 3 + 0] = h0;
  out[b * 3 + 1] = h1;
  out[b * 3 + 2] = h2;
}

extern "C" void kernel_launch(void* const* d_in, const int* in_sizes, int n_in,
                              void* d_out, int out_size, void* d_ws,
                              size_t ws_size, hipStream_t stream) {
  const float* x = (const float*)d_in[0];
  const int* lraw = (const int*)d_in[1];
  const float* W_ih = (const float*)d_in[2];
  const float* W_hh = (const float*)d_in[3];
  const float* b_ih = (const float*)d_in[4];
  const float* b_hh = (const float*)d_in[5];
  float* out = (float*)d_out;

  rnn_fused_kernel<<<B_, 256, 0, stream>>>(x, lraw, W_ih, W_hh, b_ih, b_hh,
                                           out);
}